// Round 1
// 93.745 us; speedup vs baseline: 1.0195x; 1.0195x over previous
//
#include <hip/hip_runtime.h>
#include <math.h>

#define BB 256      // batch
#define CC 1024     // channels
#define CC4 (CC/4)  // row length in float4
#define MARGIN 0.5f
#define NTILE 64    // j-tiles (of 4) per row
#define JPT 4       // j's per tile
#define NP  128     // i-pairs

// ---------------------------------------------------------------------------
// Kernel A: mcsq[i,c] = m_counts[i,c]^2 (float).
// One wave per row i. Partner selection via ballot; float4 loads.
// Block 0 also zero-inits the final-reduce accumulator + counter.
// ---------------------------------------------------------------------------
__global__ __launch_bounds__(64) void mcsq_kernel(
    const float* __restrict__ x, const int* __restrict__ targets,
    const int* __restrict__ subs, const int* __restrict__ m_count_p,
    float* __restrict__ mcsq, float* __restrict__ acc,
    unsigned int* __restrict__ cnt_g)
{
    const int i = blockIdx.x;
    const int lane = threadIdx.x;
    if (i == 0 && lane == 0) { *acc = 0.f; *cnt_g = 0u; }
    const int ti = targets[i], si = subs[i];
    int mc = *m_count_p;
    if (mc > 8) mc = 8;

    unsigned long long masks[4];
    #pragma unroll
    for (int q = 0; q < 4; ++q) {
        const int j = q * 64 + lane;
        masks[q] = __ballot(targets[j] == ti && subs[j] == si);
    }
    int idx[8];
    int cnt = 0;
    for (int q = 0; q < 4 && cnt < mc; ++q) {
        unsigned long long m = masks[q];
        while (m && cnt < mc) {
            const int b = __ffsll(m) - 1;
            idx[cnt++] = q * 64 + b;
            m &= m - 1;
        }
    }
    for (int q = 0; q < 4 && cnt < mc; ++q) {   // stable-argsort padding
        unsigned long long m = ~masks[q];
        while (m && cnt < mc) {
            const int b = __ffsll(m) - 1;
            idx[cnt++] = q * 64 + b;
            m &= m - 1;
        }
    }

    const float4* x4 = (const float4*)x;
    float4 xi[4];
    #pragma unroll
    for (int t = 0; t < 4; ++t) xi[t] = x4[(long)i * CC4 + lane + 64 * t];

    float4 c4[4];
    #pragma unroll
    for (int t = 0; t < 4; ++t) c4[t] = make_float4(0.f, 0.f, 0.f, 0.f);

    for (int k = 0; k < cnt; ++k) {
        float4 ad[4];
        float s = 0.f;
        #pragma unroll
        for (int t = 0; t < 4; ++t) {
            const float4 xj = x4[(long)idx[k] * CC4 + lane + 64 * t];
            ad[t].x = fabsf(xi[t].x - xj.x);
            ad[t].y = fabsf(xi[t].y - xj.y);
            ad[t].z = fabsf(xi[t].z - xj.z);
            ad[t].w = fabsf(xi[t].w - xj.w);
            s += ad[t].x + ad[t].y + ad[t].z + ad[t].w;
        }
        #pragma unroll
        for (int off = 32; off > 0; off >>= 1) s += __shfl_xor(s, off, 64);
        const float thr = s * (MARGIN / CC);   // 0.5 * mean
        #pragma unroll
        for (int t = 0; t < 4; ++t) {
            c4[t].x += (ad[t].x < thr) ? 1.f : 0.f;
            c4[t].y += (ad[t].y < thr) ? 1.f : 0.f;
            c4[t].z += (ad[t].z < thr) ? 1.f : 0.f;
            c4[t].w += (ad[t].w < thr) ? 1.f : 0.f;
        }
    }
    float4* m4 = (float4*)mcsq;
    #pragma unroll
    for (int t = 0; t < 4; ++t) {
        float4 o;
        o.x = c4[t].x * c4[t].x;
        o.y = c4[t].y * c4[t].y;
        o.z = c4[t].z * c4[t].z;
        o.w = c4[t].w * c4[t].w;
        m4[(long)i * CC4 + lane + 64 * t] = o;
    }
}

// ---------------------------------------------------------------------------
// Kernel B: TRIANGULAR pair kernel, 2-j software pipeline.
// Each unordered pair computed once; wave = 2 i-rows x 4 j's, processed as
// two (jA,jB) pairs. Per pair-of-j: load xA,xB -> 4 L1 sums -> issue mcsq
// loads (latency covered by the 4-var butterfly) -> masked passes for both
// j's -> one 8-var butterfly (8 independent chains). This halves the number
// of serial shuffle-chain traversals per wave vs. the 1-j-at-a-time version.
// Arithmetic order per (pair, j) is IDENTICAL to the previous kernel, so
// results bit-match (absmax must stay 0).
// ---------------------------------------------------------------------------
__global__ __launch_bounds__(256) void pair_kernel(
    const float* __restrict__ x, const float* __restrict__ mcsq,
    const int* __restrict__ targets,
    float* __restrict__ pmax, float* __restrict__ pmin,
    float* __restrict__ pmaxT, float* __restrict__ pminT)
{
    const int tid  = threadIdx.x;
    const int lane = tid & 63;
    const int gw   = blockIdx.x * 4 + (tid >> 6);  // 0..4159

    int h = (int)((129.0f - sqrtf(16641.0f - 4.0f * (float)gw)) * 0.5f);
    if (h > 63) h = 63;
    if (h < 0) h = 0;
    while (h > 0 && (129 * h - h * h) > gw) --h;
    while ((129 * (h + 1) - (h + 1) * (h + 1)) <= gw) ++h;
    const int r     = gw - (129 * h - h * h);
    const int cnt_h = 64 - h;
    const int p     = 2 * h + r / cnt_h;
    const int jt    = h + r % cnt_h;

    const int i0 = 2 * p, i1 = 2 * p + 1;

    const float4* x4 = (const float4*)x;
    const float4* m4 = (const float4*)mcsq;

    float4 xi0[4], xi1[4], mi0[4], mi1[4];
    #pragma unroll
    for (int t = 0; t < 4; ++t) {
        const int c4 = lane + 64 * t;
        xi0[t] = x4[(long)i0 * CC4 + c4];
        xi1[t] = x4[(long)i1 * CC4 + c4];
        mi0[t] = m4[(long)i0 * CC4 + c4];
        mi1[t] = m4[(long)i1 * CC4 + c4];
    }
    const int t0 = targets[i0], t1 = targets[i1];

    float max0 = 0.f, max1 = 0.f;
    float min0 = INFINITY, min1 = INFINITY;

    #pragma unroll
    for (int half = 0; half < 2; ++half) {
        const int ja = jt * JPT + 2 * half;
        const int jb = ja + 1;
        const int tja = targets[ja], tjb = targets[jb];

        // --- load x rows for both j's -----------------------------------
        float4 xa[4], xb[4];
        #pragma unroll
        for (int t = 0; t < 4; ++t) {
            const int c4 = lane + 64 * t;
            xa[t] = x4[(long)ja * CC4 + c4];
            xb[t] = x4[(long)jb * CC4 + c4];
        }

        // --- L1 partial sums, 4 (row, j) combos -------------------------
        float s0a = 0.f, s1a = 0.f, s0b = 0.f, s1b = 0.f;
        #pragma unroll
        for (int t = 0; t < 4; ++t) {
            s0a += fabsf(xi0[t].x - xa[t].x) + fabsf(xi0[t].y - xa[t].y)
                 + fabsf(xi0[t].z - xa[t].z) + fabsf(xi0[t].w - xa[t].w);
            s1a += fabsf(xi1[t].x - xa[t].x) + fabsf(xi1[t].y - xa[t].y)
                 + fabsf(xi1[t].z - xa[t].z) + fabsf(xi1[t].w - xa[t].w);
            s0b += fabsf(xi0[t].x - xb[t].x) + fabsf(xi0[t].y - xb[t].y)
                 + fabsf(xi0[t].z - xb[t].z) + fabsf(xi0[t].w - xb[t].w);
            s1b += fabsf(xi1[t].x - xb[t].x) + fabsf(xi1[t].y - xb[t].y)
                 + fabsf(xi1[t].z - xb[t].z) + fabsf(xi1[t].w - xb[t].w);
        }

        // --- issue mcsq loads; latency covered by the butterfly below ---
        float4 maa[4], mab[4];
        #pragma unroll
        for (int t = 0; t < 4; ++t) {
            const int c4 = lane + 64 * t;
            maa[t] = m4[(long)ja * CC4 + c4];
            mab[t] = m4[(long)jb * CC4 + c4];
        }

        // --- 4-var butterfly (4 independent chains) ---------------------
        #pragma unroll
        for (int off = 32; off > 0; off >>= 1) {
            s0a += __shfl_xor(s0a, off, 64);
            s1a += __shfl_xor(s1a, off, 64);
            s0b += __shfl_xor(s0b, off, 64);
            s1b += __shfl_xor(s1b, off, 64);
        }
        const float thr0a = s0a * (MARGIN / CC);
        const float thr1a = s1a * (MARGIN / CC);
        const float thr0b = s0b * (MARGIN / CC);
        const float thr1b = s1b * (MARGIN / CC);

        // --- masked passes for both j's (8 independent accumulators) ----
        float ids0a = 0.f, ids1a = 0.f, md0a = 0.f, md1a = 0.f;
        float ids0b = 0.f, ids1b = 0.f, md0b = 0.f, md1b = 0.f;
        #pragma unroll
        for (int t = 0; t < 4; ++t) {
            #pragma unroll
            for (int u = 0; u < 4; ++u) {
                const float x0v  = (&xi0[t].x)[u];
                const float x1v  = (&xi1[t].x)[u];
                const float m0v  = (&mi0[t].x)[u];
                const float m1v  = (&mi1[t].x)[u];
                const float xav  = (&xa[t].x)[u];
                const float mav  = (&maa[t].x)[u];
                const float xbv  = (&xb[t].x)[u];
                const float mbv  = (&mab[t].x)[u];

                const float d0a = x0v - xav;
                const float q0a = d0a * d0a;
                ids0a += (fabsf(d0a) < thr0a) ? q0a : 0.f;
                md0a  += q0a * m0v * mav;
                const float d1a = x1v - xav;
                const float q1a = d1a * d1a;
                ids1a += (fabsf(d1a) < thr1a) ? q1a : 0.f;
                md1a  += q1a * m1v * mav;

                const float d0b = x0v - xbv;
                const float q0b = d0b * d0b;
                ids0b += (fabsf(d0b) < thr0b) ? q0b : 0.f;
                md0b  += q0b * m0v * mbv;
                const float d1b = x1v - xbv;
                const float q1b = d1b * d1b;
                ids1b += (fabsf(d1b) < thr1b) ? q1b : 0.f;
                md1b  += q1b * m1v * mbv;
            }
        }

        // --- 8-var butterfly (8 independent chains) ---------------------
        #pragma unroll
        for (int off = 32; off > 0; off >>= 1) {
            ids0a += __shfl_xor(ids0a, off, 64);
            ids1a += __shfl_xor(ids1a, off, 64);
            md0a  += __shfl_xor(md0a,  off, 64);
            md1a  += __shfl_xor(md1a,  off, 64);
            ids0b += __shfl_xor(ids0b, off, 64);
            ids1b += __shfl_xor(ids1b, off, 64);
            md0b  += __shfl_xor(md0b,  off, 64);
            md1b  += __shfl_xor(md1b,  off, 64);
        }

        // --- epilogue, jA first then jB (same order as before) ----------
        const float mod0a = sqrtf(fmaxf(md0a, 1e-12f));
        const float mod1a = sqrtf(fmaxf(md1a, 1e-12f));
        const float mod0b = sqrtf(fmaxf(md0b, 1e-12f));
        const float mod1b = sqrtf(fmaxf(md1b, 1e-12f));
        max0 = fmaxf(fmaxf(max0, mod0a), mod0b);
        max1 = fmaxf(fmaxf(max1, mod1a), mod1b);

        float id0a = sqrtf(fmaxf(ids0a, 1e-12f));
        float id1a = sqrtf(fmaxf(ids1a, 1e-12f));
        float id0b = sqrtf(fmaxf(ids0b, 1e-12f));
        float id1b = sqrtf(fmaxf(ids1b, 1e-12f));

        if (tja != t0) min0 = fminf(min0, id0a); else id0a = INFINITY;
        if (tja != t1) min1 = fminf(min1, id1a); else id1a = INFINITY;
        if (tjb != t0) min0 = fminf(min0, id0b); else id0b = INFINITY;
        if (tjb != t1) min1 = fminf(min1, id1b); else id1b = INFINITY;

        if (lane == 0) {                       // j-side (transposed) partials
            pmaxT[ja * NP + p] = fmaxf(mod0a, mod1a);
            pminT[ja * NP + p] = fminf(id0a, id1a);
            pmaxT[jb * NP + p] = fmaxf(mod0b, mod1b);
            pminT[jb * NP + p] = fminf(id0b, id1b);
        }
    }

    if (lane == 0) {                           // i-side partials
        pmax[i0 * NTILE + jt] = max0;
        pmax[i1 * NTILE + jt] = max1;
        pmin[i0 * NTILE + jt] = min0;
        pmin[i1 * NTILE + jt] = min1;
    }
}

// ---------------------------------------------------------------------------
// Kernel C: parallel final reduce. One wave per row: <=3 guarded loads per
// lane, 6-step max/min butterfly, atomicAdd of per_row/BB; last block
// publishes the total to d_out. Valid slots: i-side jt in [i/4, 64),
// transposed p < 2*(i/4)+2 — poisoned slots never read.
// ---------------------------------------------------------------------------
__global__ __launch_bounds__(64) void final_kernel(
    const float* __restrict__ pmax, const float* __restrict__ pmin,
    const float* __restrict__ pmaxT, const float* __restrict__ pminT,
    float* __restrict__ acc, unsigned int* __restrict__ cnt_g,
    float* __restrict__ out)
{
    const int i = blockIdx.x;       // row
    const int lane = threadIdx.x;
    const int s = i >> 2;
    float mx = 0.f, mn = INFINITY;
    const int t = s + lane;
    if (t < NTILE) {
        mx = fmaxf(mx, pmax[i * NTILE + t]);
        mn = fminf(mn, pmin[i * NTILE + t]);
    }
    const int pv = 2 * s + 2;
    if (lane < pv) {
        mx = fmaxf(mx, pmaxT[i * NP + lane]);
        mn = fminf(mn, pminT[i * NP + lane]);
    }
    if (lane + 64 < pv) {
        mx = fmaxf(mx, pmaxT[i * NP + lane + 64]);
        mn = fminf(mn, pminT[i * NP + lane + 64]);
    }
    #pragma unroll
    for (int off = 32; off > 0; off >>= 1) {
        mx = fmaxf(mx, __shfl_xor(mx, off, 64));
        mn = fminf(mn, __shfl_xor(mn, off, 64));
    }
    if (lane == 0) {
        const float per = fmaxf(mx * 10.f - mn, 0.f);
        atomicAdd(acc, per * (1.0f / BB));
        __threadfence();
        const unsigned int old = atomicAdd(cnt_g, 1u);
        if (old == BB - 1) {
            __threadfence();
            out[0] = atomicAdd(acc, 0.0f);   // device-coherent read-back
        }
    }
}

extern "C" void kernel_launch(void* const* d_in, const int* in_sizes, int n_in,
                              void* d_out, int out_size, void* d_ws, size_t ws_size,
                              hipStream_t stream)
{
    const float* x       = (const float*)d_in[0];
    const int*   targets = (const int*)d_in[1];
    const int*   subs    = (const int*)d_in[2];
    const int*   m_count = (const int*)d_in[3];
    float* out  = (float*)d_out;

    float* mcsq  = (float*)d_ws;                  // BB*CC floats = 1 MB
    float* pmax  = mcsq  + (long)BB * CC;         // BB*NTILE
    float* pmin  = pmax  + BB * NTILE;            // BB*NTILE
    float* pmaxT = pmin  + BB * NTILE;            // BB*NP
    float* pminT = pmaxT + BB * NP;               // BB*NP
    float* acc   = pminT + BB * NP;               // 1
    unsigned int* cnt_g = (unsigned int*)(acc + 1);

    mcsq_kernel <<<BB,   64, 0, stream>>>(x, targets, subs, m_count, mcsq, acc, cnt_g);
    pair_kernel <<<1040, 256, 0, stream>>>(x, mcsq, targets, pmax, pmin, pmaxT, pminT);
    final_kernel<<<BB,   64, 0, stream>>>(pmax, pmin, pmaxT, pminT, acc, cnt_g, out);
}